// Round 7
// baseline (445.071 us; speedup 1.0000x reference)
//
#include <hip/hip_runtime.h>
#include <hip/hip_bf16.h>
#include <math.h>

#define BQn 2
#define QN 13294
#define SN 13294
#define NH 8
#define DH 32
#define DM 256

typedef __attribute__((ext_vector_type(8))) short short8;
typedef __attribute__((ext_vector_type(4))) float f32x4;

__device__ __forceinline__ unsigned short f2bf(float x) {
    union { float f; unsigned int u; } c; c.f = x;
    unsigned int r = c.u + 0x7fff + ((c.u >> 16) & 1);   // RNE
    return (unsigned short)(r >> 16);
}
__device__ __forceinline__ float asf(unsigned int u) {
    union { unsigned int i; float f; } c; c.i = u; return c.f;
}

// ---------------------------------------------------------------------------
// Fused transpose+bf16 of all four weight matrices: W[K][N] -> WT[N][K]
// WoffT/WaT are adjacent, forming WcatT[384][256] for the merged GEMM.
// ---------------------------------------------------------------------------
__global__ __launch_bounds__(256) void conv_weights(
    const float* __restrict__ Wv, const float* __restrict__ Woff,
    const float* __restrict__ Wa, const float* __restrict__ Wout,
    unsigned short* __restrict__ WvT, unsigned short* __restrict__ WoffT,
    unsigned short* __restrict__ WaT, unsigned short* __restrict__ WoutT)
{
    const int t = blockIdx.x * 256 + threadIdx.x;
    if (t < 65536) {
        const int n = t & 255, k = t >> 8;
        WvT[(size_t)n * 256 + k] = f2bf(Wv[(size_t)k * 256 + n]);
    } else if (t < 131072) {
        const int i = t - 65536, n = i & 255, k = i >> 8;
        WoffT[(size_t)n * 256 + k] = f2bf(Woff[(size_t)k * 256 + n]);
    } else if (t < 163840) {
        const int i = t - 131072, n = i & 127, k = i >> 7;
        WaT[(size_t)n * 256 + k] = f2bf(Wa[(size_t)k * 128 + n]);
    } else if (t < 229376) {
        const int i = t - 163840, n = i & 255, k = i >> 8;
        WoutT[(size_t)n * 256 + k] = f2bf(Wout[(size_t)k * 256 + n]);
    }
}

// ---------------------------------------------------------------------------
// bf16 MFMA GEMM: C[M,N] = A[M,256] @ WT[N,256]^T + bias
// 128x128 tile, 4 waves (2x2), each wave 64x64 via 4x4 16x16x32 fragments.
// AF32: A is fp32, converted to bf16 in staging (v_cvt_pk_bf16_f32).
// Bias split at col 256: col<256 -> bias0[col], else bias1[col-256].
// MODE 0: fp32 row-major C[M,N]; MODE 1: bf16 value layout C[b][h][s][dh].
// ---------------------------------------------------------------------------
template<int N, int MODE, bool AF32>
__global__ __launch_bounds__(256) void gemm_mfma(
    const void* __restrict__ Av,            // [M][256] fp32 or bf16
    const unsigned short* __restrict__ WT,  // [N][256] bf16
    const float* __restrict__ bias0,        // [min(N,256)] fp32
    const float* __restrict__ bias1,        // [N-256] fp32 (if N>256)
    void* __restrict__ Cv, int M)
{
    __shared__ unsigned short As[128][72];  // +8 pad: 2-way alias only (free)
    __shared__ unsigned short Bs[128][72];
    const int tid  = threadIdx.x;
    const int lane = tid & 63, wid = tid >> 6;
    const int wr = wid >> 1, wc = wid & 1;
    const int r0 = blockIdx.y * 128, n0 = blockIdx.x * 128;

    f32x4 acc[4][4] = {};

    for (int k0 = 0; k0 < 256; k0 += 64) {
        #pragma unroll
        for (int i = 0; i < 4; ++i) {           // A tile 128x64
            const int idx = i * 256 + tid;
            const int row = idx >> 3, ch = (idx & 7) << 3;
            int grow = r0 + row; if (grow >= M) grow = M - 1;
            if (AF32) {
                const float* Af = (const float*)Av;
                const float4 v0 = *(const float4*)(Af + (size_t)grow * 256 + k0 + ch);
                const float4 v1 = *(const float4*)(Af + (size_t)grow * 256 + k0 + ch + 4);
                union { __hip_bfloat162 b[4]; uint4 u; } pk;
                pk.b[0] = __float22bfloat162_rn(make_float2(v0.x, v0.y));
                pk.b[1] = __float22bfloat162_rn(make_float2(v0.z, v0.w));
                pk.b[2] = __float22bfloat162_rn(make_float2(v1.x, v1.y));
                pk.b[3] = __float22bfloat162_rn(make_float2(v1.z, v1.w));
                *(uint4*)&As[row][ch] = pk.u;
            } else {
                const unsigned short* Ab = (const unsigned short*)Av;
                *(uint4*)&As[row][ch] =
                    *(const uint4*)(Ab + (size_t)grow * 256 + k0 + ch);
            }
        }
        #pragma unroll
        for (int i = 0; i < 4; ++i) {           // B tile 128x64 (rows = N cols)
            const int idx = i * 256 + tid;
            const int row = idx >> 3, ch = (idx & 7) << 3;
            *(uint4*)&Bs[row][ch] =
                *(const uint4*)(WT + (size_t)(n0 + row) * 256 + k0 + ch);
        }
        __syncthreads();
        #pragma unroll
        for (int kk = 0; kk < 2; ++kk) {
            const int kb = kk * 32 + (lane >> 4) * 8;
            short8 bfr[4];
            #pragma unroll
            for (int n = 0; n < 4; ++n)
                bfr[n] = *(const short8*)&Bs[wc * 64 + n * 16 + (lane & 15)][kb];
            #pragma unroll
            for (int m = 0; m < 4; ++m) {
                const short8 afr =
                    *(const short8*)&As[wr * 64 + m * 16 + (lane & 15)][kb];
                #pragma unroll
                for (int n = 0; n < 4; ++n)
                    acc[m][n] = __builtin_amdgcn_mfma_f32_16x16x32_bf16(
                        afr, bfr[n], acc[m][n], 0, 0, 0);
            }
        }
        __syncthreads();
    }

    #pragma unroll
    for (int m = 0; m < 4; ++m)
        #pragma unroll
        for (int n = 0; n < 4; ++n) {
            const int col = n0 + wc * 64 + n * 16 + (lane & 15);
            const float bsv = (col < 256) ? bias0[col] : bias1[col - 256];
            #pragma unroll
            for (int j = 0; j < 4; ++j) {
                const int row = r0 + wr * 64 + m * 16 + (lane >> 4) * 4 + j;
                if (row >= M) continue;
                const float v = acc[m][n][j] + bsv;
                if (MODE == 0) {
                    ((float*)Cv)[(size_t)row * N + col] = v;
                } else {
                    const int b = (row >= SN), s = row - b * SN;
                    const int h = col >> 5, dh = col & 31;
                    ((unsigned short*)Cv)
                        [(((size_t)b * NH + h) * SN + s) * DH + dh] = f2bf(v);
                }
            }
        }
}

// ---------------------------------------------------------------------------
// Deformable sampling v4: block = (head, 64-query chunk); h = blockIdx.x & 7
// pins each head's two bf16 value planes (2 x 0.85 MB) in one XCD's L2.
// 4 lanes per (b,q,h); lane lc owns LEVEL lc (its 4 points) and channels
// [8lc,8lc+8) -> uint4 (16B) gathers, 8 FMA per corner: ~3.6 VALU ops/channel
// vs 5 in the 8-lane version, and coord math replicated 4x not 8x.
// ---------------------------------------------------------------------------
__global__ __launch_bounds__(256) void ms_sample(
    const unsigned short* __restrict__ value, // [B,H,S,32] bf16
    const float* __restrict__ offaw,          // [B*Q,384] (256 off | 128 logits)
    const float* __restrict__ refp,           // [B,Q,4,2]
    unsigned short* __restrict__ outh,        // [B,Q,256] bf16
    float* __restrict__ awout)                // [B,Q,128]
{
    const int h  = blockIdx.x & 7;
    const int qc = blockIdx.x >> 3;
    const int lc = threadIdx.x & 3;           // lane-in-group == level
    const int bq = qc * 64 + (threadIdx.x >> 2);
    if (bq >= BQn * QN) return;
    const int b  = (bq >= QN);
    const int gbase = threadIdx.x & 60;

    const float* rowp = offaw + (size_t)bq * 384;

    // distributed softmax over 16 logits: 4 per lane, 4-lane reduce
    const float4 lg = *(const float4*)(rowp + 256 + h * 16 + lc * 4);
    float m = fmaxf(fmaxf(lg.x, lg.y), fmaxf(lg.z, lg.w));
    m = fmaxf(m, __shfl_xor(m, 1, 4));
    m = fmaxf(m, __shfl_xor(m, 2, 4));
    float e0 = __expf(lg.x - m), e1 = __expf(lg.y - m),
          e2 = __expf(lg.z - m), e3 = __expf(lg.w - m);
    float s = (e0 + e1) + (e2 + e3);
    s += __shfl_xor(s, 1, 4);
    s += __shfl_xor(s, 2, 4);
    const float inv = 1.f / s;
    e0 *= inv; e1 *= inv; e2 *= inv; e3 *= inv;
    *(float4*)(awout + (size_t)bq * 128 + h * 16 + lc * 4) =
        make_float4(e0, e1, e2, e3);

    // this lane's level: 4 points, 8 offset floats
    const float4 oa = *(const float4*)(rowp + h * 32 + lc * 8);
    const float4 ob = *(const float4*)(rowp + h * 32 + lc * 8 + 4);
    const float2 rp = *(const float2*)(refp + (size_t)bq * 8 + lc * 2);
    const float rw = (lc == 0) ? 0.01f : (lc == 1) ? 0.02f
                   : (lc == 2) ? 0.04f : (1.0f / 13.0f);
    const float lx0 = fmaf(oa.x, rw, rp.x), ly0 = fmaf(oa.y, rw, rp.y);
    const float lx1 = fmaf(oa.z, rw, rp.x), ly1 = fmaf(oa.w, rw, rp.y);
    const float lx2 = fmaf(ob.x, rw, rp.x), ly2 = fmaf(ob.y, rw, rp.y);
    const float lx3 = fmaf(ob.z, rw, rp.x), ly3 = fmaf(ob.w, rw, rp.y);

    float a0 = 0.f, a1 = 0.f, a2 = 0.f, a3 = 0.f,
          a4 = 0.f, a5 = 0.f, a6 = 0.f, a7 = 0.f;
    const unsigned short* vplane =
        value + (((size_t)b * NH + h) * SN) * DH + lc * 8;

    #pragma unroll
    for (int p = 0; p < 16; ++p) {
        constexpr int LW[4]  = {100, 50, 25, 13};
        constexpr int LST[4] = {0, 10000, 12500, 13125};
        const int l  = p >> 2;
        const int w  = LW[l];
        const int st = LST[l];
        const int src = gbase + l;
        const int pi = p & 3;
        const float lx = __shfl(pi == 0 ? lx0 : pi == 1 ? lx1 : pi == 2 ? lx2 : lx3, src, 64);
        const float ly = __shfl(pi == 0 ? ly0 : pi == 1 ? ly1 : pi == 2 ? ly2 : ly3, src, 64);
        const float wt = __shfl(pi == 0 ? e0  : pi == 1 ? e1  : pi == 2 ? e2  : e3,  src, 64);

        const float x = fmaf(lx, (float)w, -0.5f);
        const float y = fmaf(ly, (float)w, -0.5f);
        const float x0f = floorf(x), y0f = floorf(y);
        const int x0 = (int)x0f, y0 = (int)y0f;
        const float wx1 = x - x0f, wx0 = 1.f - wx1;
        const float wy1 = y - y0f, wy0 = 1.f - wy1;

        #pragma unroll
        for (int c = 0; c < 4; ++c) {
            const int xi = x0 + (c & 1);
            const int yi = y0 + (c >> 1);
            const float cw = ((c & 1) ? wx1 : wx0) * ((c >> 1) ? wy1 : wy0);
            const bool valid = ((unsigned)xi < (unsigned)w) &
                               ((unsigned)yi < (unsigned)w);
            const float wgt = valid ? cw * wt : 0.f;
            const int xc = min(max(xi, 0), w - 1);
            const int yc = min(max(yi, 0), w - 1);
            const uint4 v =
                *(const uint4*)(vplane + (size_t)(st + yc * w + xc) * DH);
            a0 = fmaf(wgt, asf(v.x << 16),         a0);
            a1 = fmaf(wgt, asf(v.x & 0xffff0000u), a1);
            a2 = fmaf(wgt, asf(v.y << 16),         a2);
            a3 = fmaf(wgt, asf(v.y & 0xffff0000u), a3);
            a4 = fmaf(wgt, asf(v.z << 16),         a4);
            a5 = fmaf(wgt, asf(v.z & 0xffff0000u), a5);
            a6 = fmaf(wgt, asf(v.w << 16),         a6);
            a7 = fmaf(wgt, asf(v.w & 0xffff0000u), a7);
        }
    }

    union { unsigned short us[8]; uint4 u; } o;
    o.us[0] = f2bf(a0); o.us[1] = f2bf(a1); o.us[2] = f2bf(a2); o.us[3] = f2bf(a3);
    o.us[4] = f2bf(a4); o.us[5] = f2bf(a5); o.us[6] = f2bf(a6); o.us[7] = f2bf(a7);
    *(uint4*)(outh + (size_t)bq * 256 + h * 32 + lc * 8) = o.u;
}

// ---------------------------------------------------------------------------
// Workspace (~68.5 MB, NO aliasing; each region: one producer, later readers):
//   valueb [MQ*256 bf16]  <- gemm value (MODE1, fp32 A=enc)  -> ms_sample
//   offaw  [MQ*384 f32 ]  <- merged off+attn gemm (fp32 A=hs)-> ms_sample
//   outh   [MQ*256 bf16]  <- ms_sample                        -> gemm out
//   WvT/WcatT/WoutT       <- conv_weights                     -> gemms
// ---------------------------------------------------------------------------
extern "C" void kernel_launch(void* const* d_in, const int* in_sizes, int n_in,
                              void* d_out, int out_size, void* d_ws, size_t ws_size,
                              hipStream_t stream) {
    const float* hs   = (const float*)d_in[0];
    const float* enc  = (const float*)d_in[1];
    const float* refp = (const float*)d_in[2];
    const float* Wv   = (const float*)d_in[3];
    const float* bv   = (const float*)d_in[4];
    const float* Woff = (const float*)d_in[5];
    const float* boff = (const float*)d_in[6];
    const float* Wa   = (const float*)d_in[7];
    const float* ba   = (const float*)d_in[8];
    const float* Wout = (const float*)d_in[9];
    const float* bout = (const float*)d_in[10];

    float* out    = (float*)d_out;
    float* aw_out = out + (size_t)BQn * QN * 256;

    const size_t MQ = (size_t)BQn * QN;      // 26588
    unsigned short* valueb = (unsigned short*)d_ws;              // MQ*256 bf16
    float* offaw = (float*)(valueb + MQ * 256);                  // MQ*384 f32
    unsigned short* outh  = (unsigned short*)(offaw + MQ * 384); // MQ*256 bf16
    unsigned short* WvT   = outh + MQ * 256;                     // 256*256
    unsigned short* WcatT = WvT + 256 * 256;                     // 384*256
    unsigned short* WoutT = WcatT + 384 * 256;                   // 256*256

    const int M = (int)MQ;
    const dim3 blk(256);

    conv_weights<<<896, blk, 0, stream>>>(Wv, Woff, Wa, Wout,
                                          WvT, WcatT, WcatT + 65536, WoutT);

    const int my = (M + 127) / 128;           // 208
    gemm_mfma<256, 1, true ><<<dim3(2, my), blk, 0, stream>>>(
        enc, WvT, bv, bv, valueb, M);
    gemm_mfma<384, 0, true ><<<dim3(3, my), blk, 0, stream>>>(
        hs, WcatT, boff, ba, offaw, M);

    const int qchunks = (M + 63) / 64;        // 416
    ms_sample<<<8 * qchunks, blk, 0, stream>>>(valueb, offaw, refp,
                                               outh, aw_out);

    gemm_mfma<256, 0, false><<<dim3(2, my), blk, 0, stream>>>(
        outh, WoutT, bout, bout, out, M);
}

// Round 8
// 137.459 us; speedup vs baseline: 3.2378x; 3.2378x over previous
//
#include <hip/hip_runtime.h>
#include <hip/hip_bf16.h>
#include <math.h>

#define BQn 2
#define QN 13294
#define SN 13294
#define NH 8
#define DH 32
#define DM 256

typedef __attribute__((ext_vector_type(8))) short short8;
typedef __attribute__((ext_vector_type(4))) float f32x4;

__device__ __forceinline__ unsigned short f2bf(float x) {
    union { float f; unsigned int u; } c; c.f = x;
    unsigned int r = c.u + 0x7fff + ((c.u >> 16) & 1);   // RNE
    return (unsigned short)(r >> 16);
}
__device__ __forceinline__ float asf(unsigned int u) {
    union { unsigned int i; float f; } c; c.i = u; return c.f;
}

// ---------------------------------------------------------------------------
// Fused transpose+bf16 of all four weight matrices: W[K][N] -> WT[N][K]
// WoffT/WaT are adjacent, forming WcatT[384][256] for the merged GEMM.
// ---------------------------------------------------------------------------
__global__ __launch_bounds__(256) void conv_weights(
    const float* __restrict__ Wv, const float* __restrict__ Woff,
    const float* __restrict__ Wa, const float* __restrict__ Wout,
    unsigned short* __restrict__ WvT, unsigned short* __restrict__ WoffT,
    unsigned short* __restrict__ WaT, unsigned short* __restrict__ WoutT)
{
    const int t = blockIdx.x * 256 + threadIdx.x;
    if (t < 65536) {
        const int n = t & 255, k = t >> 8;
        WvT[(size_t)n * 256 + k] = f2bf(Wv[(size_t)k * 256 + n]);
    } else if (t < 131072) {
        const int i = t - 65536, n = i & 255, k = i >> 8;
        WoffT[(size_t)n * 256 + k] = f2bf(Woff[(size_t)k * 256 + n]);
    } else if (t < 163840) {
        const int i = t - 131072, n = i & 127, k = i >> 7;
        WaT[(size_t)n * 256 + k] = f2bf(Wa[(size_t)k * 128 + n]);
    } else if (t < 229376) {
        const int i = t - 163840, n = i & 255, k = i >> 8;
        WoutT[(size_t)n * 256 + k] = f2bf(Wout[(size_t)k * 256 + n]);
    }
}

// ---------------------------------------------------------------------------
// bf16 MFMA GEMM: C[M,N] = A[M,256] @ WT[N,256]^T + bias
// 128x128 tile, 4 waves (2x2), each wave 64x64 via 4x4 16x16x32 fragments.
// AF32: A is fp32, converted to bf16 in staging (v_cvt_pk_bf16_f32).
// Bias split at col 256: col<256 -> bias0[col], else bias1[col-256].
// MODE 0: fp32 row-major C[M,N]; MODE 1: bf16 value layout C[b][h][s][dh].
// ---------------------------------------------------------------------------
template<int N, int MODE, bool AF32>
__global__ __launch_bounds__(256) void gemm_mfma(
    const void* __restrict__ Av,            // [M][256] fp32 or bf16
    const unsigned short* __restrict__ WT,  // [N][256] bf16
    const float* __restrict__ bias0,        // [min(N,256)] fp32
    const float* __restrict__ bias1,        // [N-256] fp32 (if N>256)
    void* __restrict__ Cv, int M)
{
    __shared__ unsigned short As[128][72];  // +8 pad: 2-way alias only (free)
    __shared__ unsigned short Bs[128][72];
    const int tid  = threadIdx.x;
    const int lane = tid & 63, wid = tid >> 6;
    const int wr = wid >> 1, wc = wid & 1;
    const int r0 = blockIdx.y * 128, n0 = blockIdx.x * 128;

    f32x4 acc[4][4] = {};

    for (int k0 = 0; k0 < 256; k0 += 64) {
        #pragma unroll
        for (int i = 0; i < 4; ++i) {           // A tile 128x64
            const int idx = i * 256 + tid;
            const int row = idx >> 3, ch = (idx & 7) << 3;
            int grow = r0 + row; if (grow >= M) grow = M - 1;
            if (AF32) {
                const float* Af = (const float*)Av;
                const float4 v0 = *(const float4*)(Af + (size_t)grow * 256 + k0 + ch);
                const float4 v1 = *(const float4*)(Af + (size_t)grow * 256 + k0 + ch + 4);
                union { __hip_bfloat162 b[4]; uint4 u; } pk;
                pk.b[0] = __float22bfloat162_rn(make_float2(v0.x, v0.y));
                pk.b[1] = __float22bfloat162_rn(make_float2(v0.z, v0.w));
                pk.b[2] = __float22bfloat162_rn(make_float2(v1.x, v1.y));
                pk.b[3] = __float22bfloat162_rn(make_float2(v1.z, v1.w));
                *(uint4*)&As[row][ch] = pk.u;
            } else {
                const unsigned short* Ab = (const unsigned short*)Av;
                *(uint4*)&As[row][ch] =
                    *(const uint4*)(Ab + (size_t)grow * 256 + k0 + ch);
            }
        }
        #pragma unroll
        for (int i = 0; i < 4; ++i) {           // B tile 128x64 (rows = N cols)
            const int idx = i * 256 + tid;
            const int row = idx >> 3, ch = (idx & 7) << 3;
            *(uint4*)&Bs[row][ch] =
                *(const uint4*)(WT + (size_t)(n0 + row) * 256 + k0 + ch);
        }
        __syncthreads();
        #pragma unroll
        for (int kk = 0; kk < 2; ++kk) {
            const int kb = kk * 32 + (lane >> 4) * 8;
            short8 bfr[4];
            #pragma unroll
            for (int n = 0; n < 4; ++n)
                bfr[n] = *(const short8*)&Bs[wc * 64 + n * 16 + (lane & 15)][kb];
            #pragma unroll
            for (int m = 0; m < 4; ++m) {
                const short8 afr =
                    *(const short8*)&As[wr * 64 + m * 16 + (lane & 15)][kb];
                #pragma unroll
                for (int n = 0; n < 4; ++n)
                    acc[m][n] = __builtin_amdgcn_mfma_f32_16x16x32_bf16(
                        afr, bfr[n], acc[m][n], 0, 0, 0);
            }
        }
        __syncthreads();
    }

    #pragma unroll
    for (int m = 0; m < 4; ++m)
        #pragma unroll
        for (int n = 0; n < 4; ++n) {
            const int col = n0 + wc * 64 + n * 16 + (lane & 15);
            const float bsv = (col < 256) ? bias0[col] : bias1[col - 256];
            #pragma unroll
            for (int j = 0; j < 4; ++j) {
                const int row = r0 + wr * 64 + m * 16 + (lane >> 4) * 4 + j;
                if (row >= M) continue;
                const float v = acc[m][n][j] + bsv;
                if (MODE == 0) {
                    ((float*)Cv)[(size_t)row * N + col] = v;
                } else {
                    const int b = (row >= SN), s = row - b * SN;
                    const int h = col >> 5, dh = col & 31;
                    ((unsigned short*)Cv)
                        [(((size_t)b * NH + h) * SN + s) * DH + dh] = f2bf(v);
                }
            }
        }
}

// ---------------------------------------------------------------------------
// Deformable sampling (round-6 proven version: VGPR 36, occ 64%, 69 us):
// block = (head, 32-query chunk); h = blockIdx.x & 7 pins each head's two
// bf16 value planes (2 x 0.85 MB) in one XCD's L2. 8 lanes per (b,q,h);
// lane lc owns channels [4lc,4lc+4) and point-pairs 2lc,2lc+1. Branchless
// clamped corners, __expf softmax, 1-op bf16 unpacks.
// ---------------------------------------------------------------------------
__global__ __launch_bounds__(256) void ms_sample(
    const unsigned short* __restrict__ value, // [B,H,S,32] bf16
    const float* __restrict__ offaw,          // [B*Q,384] (256 off | 128 logits)
    const float* __restrict__ refp,           // [B,Q,4,2]
    unsigned short* __restrict__ outh,        // [B,Q,256] bf16
    float* __restrict__ awout)                // [B,Q,128]
{
    const int h  = blockIdx.x & 7;
    const int qc = blockIdx.x >> 3;
    const int lc = threadIdx.x & 7;
    const int bq = qc * 32 + (threadIdx.x >> 3);
    if (bq >= BQn * QN) return;
    const int b  = (bq >= QN);
    const int gbase = threadIdx.x & 56;

    const float* rowp = offaw + (size_t)bq * 384;

    // distributed softmax over 16 logits: 2 per lane
    const float2 lw2 = *(const float2*)(rowp + 256 + h * 16 + lc * 2);
    float m = fmaxf(lw2.x, lw2.y);
    #pragma unroll
    for (int d = 1; d < 8; d <<= 1) m = fmaxf(m, __shfl_xor(m, d, 8));
    float e0 = __expf(lw2.x - m), e1 = __expf(lw2.y - m);
    float s = e0 + e1;
    #pragma unroll
    for (int d = 1; d < 8; d <<= 1) s += __shfl_xor(s, d, 8);
    const float inv = 1.f / s;
    e0 *= inv; e1 *= inv;
    *(float2*)(awout + (size_t)bq * 128 + h * 16 + lc * 2) = make_float2(e0, e1);

    // this lane's two points (reciprocal-multiply, fmaf)
    const float4 o4 = *(const float4*)(rowp + h * 32 + lc * 4);
    const int lvl = lc >> 1;
    const float2 rp = *(const float2*)(refp + (size_t)bq * 8 + lvl * 2);
    const float rw = (lvl == 0) ? 0.01f : (lvl == 1) ? 0.02f
                   : (lvl == 2) ? 0.04f : (1.0f / 13.0f);
    const float lx0 = fmaf(o4.x, rw, rp.x), ly0 = fmaf(o4.y, rw, rp.y);
    const float lx1 = fmaf(o4.z, rw, rp.x), ly1 = fmaf(o4.w, rw, rp.y);

    float ax = 0.f, ay = 0.f, az = 0.f, aw_ = 0.f;
    const unsigned short* vplane =
        value + (((size_t)b * NH + h) * SN) * DH + lc * 4;

    #pragma unroll
    for (int p = 0; p < 16; ++p) {
        constexpr int LW[4]  = {100, 50, 25, 13};
        constexpr int LST[4] = {0, 10000, 12500, 13125};
        const int l  = p >> 2;
        const int w  = LW[l];
        const int st = LST[l];
        const int src = gbase + (p >> 1);
        const float lx = __shfl((p & 1) ? lx1 : lx0, src, 64);
        const float ly = __shfl((p & 1) ? ly1 : ly0, src, 64);
        const float wt = __shfl((p & 1) ? e1  : e0,  src, 64);

        const float x = fmaf(lx, (float)w, -0.5f);
        const float y = fmaf(ly, (float)w, -0.5f);
        const float x0f = floorf(x), y0f = floorf(y);
        const int x0 = (int)x0f, y0 = (int)y0f;
        const float wx1 = x - x0f, wx0 = 1.f - wx1;
        const float wy1 = y - y0f, wy0 = 1.f - wy1;

        #pragma unroll
        for (int c = 0; c < 4; ++c) {
            const int xi = x0 + (c & 1);
            const int yi = y0 + (c >> 1);
            const float cw = ((c & 1) ? wx1 : wx0) * ((c >> 1) ? wy1 : wy0);
            const bool valid = ((unsigned)xi < (unsigned)w) &
                               ((unsigned)yi < (unsigned)w);
            const float wgt = valid ? cw * wt : 0.f;
            const int xc = min(max(xi, 0), w - 1);
            const int yc = min(max(yi, 0), w - 1);
            const uint2 v =
                *(const uint2*)(vplane + (size_t)(st + yc * w + xc) * DH);
            ax  = fmaf(wgt, asf(v.x << 16),          ax);
            ay  = fmaf(wgt, asf(v.x & 0xffff0000u),  ay);
            az  = fmaf(wgt, asf(v.y << 16),          az);
            aw_ = fmaf(wgt, asf(v.y & 0xffff0000u),  aw_);
        }
    }

    ushort4 o;
    o.x = f2bf(ax); o.y = f2bf(ay); o.z = f2bf(az); o.w = f2bf(aw_);
    *(ushort4*)(outh + (size_t)bq * 256 + h * 32 + lc * 4) = o;
}

// ---------------------------------------------------------------------------
// Workspace (~68.5 MB, NO aliasing; each region: one producer, later readers):
//   valueb [MQ*256 bf16]  <- gemm value (MODE1, fp32 A=enc)  -> ms_sample
//   offaw  [MQ*384 f32 ]  <- merged off+attn gemm (fp32 A=hs)-> ms_sample
//   outh   [MQ*256 bf16]  <- ms_sample                        -> gemm out
//   WvT/WcatT/WoutT       <- conv_weights                     -> gemms
// ---------------------------------------------------------------------------
extern "C" void kernel_launch(void* const* d_in, const int* in_sizes, int n_in,
                              void* d_out, int out_size, void* d_ws, size_t ws_size,
                              hipStream_t stream) {
    const float* hs   = (const float*)d_in[0];
    const float* enc  = (const float*)d_in[1];
    const float* refp = (const float*)d_in[2];
    const float* Wv   = (const float*)d_in[3];
    const float* bv   = (const float*)d_in[4];
    const float* Woff = (const float*)d_in[5];
    const float* boff = (const float*)d_in[6];
    const float* Wa   = (const float*)d_in[7];
    const float* ba   = (const float*)d_in[8];
    const float* Wout = (const float*)d_in[9];
    const float* bout = (const float*)d_in[10];

    float* out    = (float*)d_out;
    float* aw_out = out + (size_t)BQn * QN * 256;

    const size_t MQ = (size_t)BQn * QN;      // 26588
    unsigned short* valueb = (unsigned short*)d_ws;              // MQ*256 bf16
    float* offaw = (float*)(valueb + MQ * 256);                  // MQ*384 f32
    unsigned short* outh  = (unsigned short*)(offaw + MQ * 384); // MQ*256 bf16
    unsigned short* WvT   = outh + MQ * 256;                     // 256*256
    unsigned short* WcatT = WvT + 256 * 256;                     // 384*256
    unsigned short* WoutT = WcatT + 384 * 256;                   // 256*256

    const int M = (int)MQ;
    const dim3 blk(256);

    conv_weights<<<896, blk, 0, stream>>>(Wv, Woff, Wa, Wout,
                                          WvT, WcatT, WcatT + 65536, WoutT);

    const int my = (M + 127) / 128;           // 208
    gemm_mfma<256, 1, true ><<<dim3(2, my), blk, 0, stream>>>(
        enc, WvT, bv, bv, valueb, M);
    gemm_mfma<384, 0, true ><<<dim3(3, my), blk, 0, stream>>>(
        hs, WcatT, boff, ba, offaw, M);

    const int qchunks = (M + 31) / 32;        // 831
    ms_sample<<<8 * qchunks, blk, 0, stream>>>(valueb, offaw, refp,
                                               outh, aw_out);

    gemm_mfma<256, 0, false><<<dim3(2, my), blk, 0, stream>>>(
        outh, WoutT, bout, bout, out, M);
}

// Round 9
// 136.376 us; speedup vs baseline: 3.2636x; 1.0079x over previous
//
#include <hip/hip_runtime.h>
#include <hip/hip_bf16.h>
#include <math.h>

#define BQn 2
#define QN 13294
#define SN 13294
#define NH 8
#define DH 32
#define DM 256

typedef __attribute__((ext_vector_type(8))) short short8;
typedef __attribute__((ext_vector_type(4))) float f32x4;

__device__ __forceinline__ unsigned short f2bf(float x) {
    union { float f; unsigned int u; } c; c.f = x;
    unsigned int r = c.u + 0x7fff + ((c.u >> 16) & 1);   // RNE
    return (unsigned short)(r >> 16);
}
__device__ __forceinline__ float asf(unsigned int u) {
    union { unsigned int i; float f; } c; c.i = u; return c.f;
}

// ---------------------------------------------------------------------------
// Fused transpose+bf16 of all four weight matrices: W[K][N] -> WT[N][K]
// WoffT/WaT are adjacent, forming WcatT[384][256] for the merged GEMM.
// ---------------------------------------------------------------------------
__global__ __launch_bounds__(256) void conv_weights(
    const float* __restrict__ Wv, const float* __restrict__ Woff,
    const float* __restrict__ Wa, const float* __restrict__ Wout,
    unsigned short* __restrict__ WvT, unsigned short* __restrict__ WoffT,
    unsigned short* __restrict__ WaT, unsigned short* __restrict__ WoutT)
{
    const int t = blockIdx.x * 256 + threadIdx.x;
    if (t < 65536) {
        const int n = t & 255, k = t >> 8;
        WvT[(size_t)n * 256 + k] = f2bf(Wv[(size_t)k * 256 + n]);
    } else if (t < 131072) {
        const int i = t - 65536, n = i & 255, k = i >> 8;
        WoffT[(size_t)n * 256 + k] = f2bf(Woff[(size_t)k * 256 + n]);
    } else if (t < 163840) {
        const int i = t - 131072, n = i & 127, k = i >> 7;
        WaT[(size_t)n * 256 + k] = f2bf(Wa[(size_t)k * 128 + n]);
    } else if (t < 229376) {
        const int i = t - 163840, n = i & 255, k = i >> 8;
        WoutT[(size_t)n * 256 + k] = f2bf(Wout[(size_t)k * 256 + n]);
    }
}

// ---------------------------------------------------------------------------
// bf16 MFMA GEMM: C[M,N] = A[M,256] @ WT[N,256]^T + bias
// 128x128 tile, 4 waves (2x2), each wave 64x64 via 4x4 16x16x32 fragments.
// AF32: A is fp32, converted to bf16 in staging (v_cvt_pk_bf16_f32).
// Bias split at col 256: col<256 -> bias0[col], else bias1[col-256].
// MODE 0: fp32 row-major C[M,N]; MODE 1: bf16 value layout C[b][h][s][dh].
// ---------------------------------------------------------------------------
template<int N, int MODE, bool AF32>
__global__ __launch_bounds__(256) void gemm_mfma(
    const void* __restrict__ Av,            // [M][256] fp32 or bf16
    const unsigned short* __restrict__ WT,  // [N][256] bf16
    const float* __restrict__ bias0,        // [min(N,256)] fp32
    const float* __restrict__ bias1,        // [N-256] fp32 (if N>256)
    void* __restrict__ Cv, int M)
{
    __shared__ unsigned short As[128][72];  // +8 pad: 2-way alias only (free)
    __shared__ unsigned short Bs[128][72];
    const int tid  = threadIdx.x;
    const int lane = tid & 63, wid = tid >> 6;
    const int wr = wid >> 1, wc = wid & 1;
    const int r0 = blockIdx.y * 128, n0 = blockIdx.x * 128;

    f32x4 acc[4][4] = {};

    for (int k0 = 0; k0 < 256; k0 += 64) {
        #pragma unroll
        for (int i = 0; i < 4; ++i) {           // A tile 128x64
            const int idx = i * 256 + tid;
            const int row = idx >> 3, ch = (idx & 7) << 3;
            int grow = r0 + row; if (grow >= M) grow = M - 1;
            if (AF32) {
                const float* Af = (const float*)Av;
                const float4 v0 = *(const float4*)(Af + (size_t)grow * 256 + k0 + ch);
                const float4 v1 = *(const float4*)(Af + (size_t)grow * 256 + k0 + ch + 4);
                union { __hip_bfloat162 b[4]; uint4 u; } pk;
                pk.b[0] = __float22bfloat162_rn(make_float2(v0.x, v0.y));
                pk.b[1] = __float22bfloat162_rn(make_float2(v0.z, v0.w));
                pk.b[2] = __float22bfloat162_rn(make_float2(v1.x, v1.y));
                pk.b[3] = __float22bfloat162_rn(make_float2(v1.z, v1.w));
                *(uint4*)&As[row][ch] = pk.u;
            } else {
                const unsigned short* Ab = (const unsigned short*)Av;
                *(uint4*)&As[row][ch] =
                    *(const uint4*)(Ab + (size_t)grow * 256 + k0 + ch);
            }
        }
        #pragma unroll
        for (int i = 0; i < 4; ++i) {           // B tile 128x64 (rows = N cols)
            const int idx = i * 256 + tid;
            const int row = idx >> 3, ch = (idx & 7) << 3;
            *(uint4*)&Bs[row][ch] =
                *(const uint4*)(WT + (size_t)(n0 + row) * 256 + k0 + ch);
        }
        __syncthreads();
        #pragma unroll
        for (int kk = 0; kk < 2; ++kk) {
            const int kb = kk * 32 + (lane >> 4) * 8;
            short8 bfr[4];
            #pragma unroll
            for (int n = 0; n < 4; ++n)
                bfr[n] = *(const short8*)&Bs[wc * 64 + n * 16 + (lane & 15)][kb];
            #pragma unroll
            for (int m = 0; m < 4; ++m) {
                const short8 afr =
                    *(const short8*)&As[wr * 64 + m * 16 + (lane & 15)][kb];
                #pragma unroll
                for (int n = 0; n < 4; ++n)
                    acc[m][n] = __builtin_amdgcn_mfma_f32_16x16x32_bf16(
                        afr, bfr[n], acc[m][n], 0, 0, 0);
            }
        }
        __syncthreads();
    }

    #pragma unroll
    for (int m = 0; m < 4; ++m)
        #pragma unroll
        for (int n = 0; n < 4; ++n) {
            const int col = n0 + wc * 64 + n * 16 + (lane & 15);
            const float bsv = (col < 256) ? bias0[col] : bias1[col - 256];
            #pragma unroll
            for (int j = 0; j < 4; ++j) {
                const int row = r0 + wr * 64 + m * 16 + (lane >> 4) * 4 + j;
                if (row >= M) continue;
                const float v = acc[m][n][j] + bsv;
                if (MODE == 0) {
                    ((float*)Cv)[(size_t)row * N + col] = v;
                } else {
                    const int b = (row >= SN), s = row - b * SN;
                    const int h = col >> 5, dh = col & 31;
                    ((unsigned short*)Cv)
                        [(((size_t)b * NH + h) * SN + s) * DH + dh] = f2bf(v);
                }
            }
        }
}

// ---------------------------------------------------------------------------
// Deformable sampling v5 (owner-compute): block = (head, 32-query chunk);
// h = blockIdx.x & 7 pins each head's two bf16 value planes in one XCD's L2.
// 8 lanes per (b,q,h); lane lc owns channels [4lc,4lc+4) AND point-pairs
// 2lc,2lc+1. Owner precomputes per point: clamped row offsets (incl. level
// start), clamped cols, and bilinear weights with validity+attention-weight
// folded in (invalid axis -> weight 0, so clamped gather * 0 = 0). Per point
// the group shfl-broadcasts 8 results (LDS pipe, overlaps VALU); per corner
// only {add, mul, addr, load, 4 unpack, 4 FMA} remain.
// ---------------------------------------------------------------------------
__global__ __launch_bounds__(256) void ms_sample(
    const unsigned short* __restrict__ value, // [B,H,S,32] bf16
    const float* __restrict__ offaw,          // [B*Q,384] (256 off | 128 logits)
    const float* __restrict__ refp,           // [B,Q,4,2]
    unsigned short* __restrict__ outh,        // [B,Q,256] bf16
    float* __restrict__ awout)                // [B,Q,128]
{
    const int h  = blockIdx.x & 7;
    const int qc = blockIdx.x >> 3;
    const int lc = threadIdx.x & 7;
    const int bq = qc * 32 + (threadIdx.x >> 3);
    if (bq >= BQn * QN) return;
    const int b  = (bq >= QN);
    const int gbase = threadIdx.x & 56;

    const float* rowp = offaw + (size_t)bq * 384;

    // distributed softmax over 16 logits: 2 per lane
    const float2 lw2 = *(const float2*)(rowp + 256 + h * 16 + lc * 2);
    float m = fmaxf(lw2.x, lw2.y);
    #pragma unroll
    for (int d = 1; d < 8; d <<= 1) m = fmaxf(m, __shfl_xor(m, d, 8));
    float e0 = __expf(lw2.x - m), e1 = __expf(lw2.y - m);
    float s = e0 + e1;
    #pragma unroll
    for (int d = 1; d < 8; d <<= 1) s += __shfl_xor(s, d, 8);
    const float inv = 1.f / s;
    e0 *= inv; e1 *= inv;
    *(float2*)(awout + (size_t)bq * 128 + h * 16 + lc * 2) = make_float2(e0, e1);

    // ---- owner precompute: this lane's level constants + its two points ----
    const int lvl = lc >> 1;
    const int wi  = (lvl == 0) ? 100 : (lvl == 1) ? 50 : (lvl == 2) ? 25 : 13;
    const float fw = (float)wi;
    const int sti = (lvl == 0) ? 0 : (lvl == 1) ? 10000 : (lvl == 2) ? 12500 : 13125;
    const float rw = (lvl == 0) ? 0.01f : (lvl == 1) ? 0.02f
                   : (lvl == 2) ? 0.04f : (1.0f / 13.0f);
    const float2 rp = *(const float2*)(refp + (size_t)bq * 8 + lvl * 2);
    const float4 o4 = *(const float4*)(rowp + h * 32 + lc * 4);

    int   rA0, rB0, cA0, cB0, rA1, rB1, cA1, cB1;
    float wxA0, wxB0, wyA0, wyB0, wxA1, wxB1, wyA1, wyB1;

    auto prep = [&](float ox, float oy, float ek,
                    int& rA, int& rB, int& cA, int& cB,
                    float& wxA, float& wxB, float& wyA, float& wyB) {
        const float x = fmaf(fmaf(ox, rw, rp.x), fw, -0.5f);
        const float y = fmaf(fmaf(oy, rw, rp.y), fw, -0.5f);
        const float x0f = floorf(x), y0f = floorf(y);
        const int ix = (int)x0f, iy = (int)y0f;
        const float wx1 = x - x0f, wy1 = y - y0f;
        wxA = ((unsigned)ix        < (unsigned)wi) ? 1.f - wx1 : 0.f;
        wxB = ((unsigned)(ix + 1)  < (unsigned)wi) ? wx1       : 0.f;
        wyA = (((unsigned)iy       < (unsigned)wi) ? 1.f - wy1 : 0.f) * ek;
        wyB = (((unsigned)(iy + 1) < (unsigned)wi) ? wy1       : 0.f) * ek;
        const int xc0 = min(max(ix, 0),     wi - 1);
        const int xc1 = min(max(ix + 1, 0), wi - 1);
        const int yc0 = min(max(iy, 0),     wi - 1);
        const int yc1 = min(max(iy + 1, 0), wi - 1);
        rA = sti + yc0 * wi; rB = sti + yc1 * wi;
        cA = xc0;            cB = xc1;
    };
    prep(o4.x, o4.y, e0, rA0, rB0, cA0, cB0, wxA0, wxB0, wyA0, wyB0);
    prep(o4.z, o4.w, e1, rA1, rB1, cA1, cB1, wxA1, wxB1, wyA1, wyB1);

    // uniform base for head-plane, per-lane 32-bit byte offset (b, lc folded)
    const char* hplane = (const char*)(value + (size_t)h * SN * DH);
    const unsigned lnoff = (unsigned)b * (NH * SN * DH * 2) + lc * 8;

    float ax = 0.f, ay = 0.f, az = 0.f, aw_ = 0.f;

    #pragma unroll
    for (int p = 0; p < 16; ++p) {
        const int src = gbase + (p >> 1);
        const int   rA  = __shfl((p & 1) ? rA1  : rA0,  src, 64);
        const int   rB  = __shfl((p & 1) ? rB1  : rB0,  src, 64);
        const int   cA  = __shfl((p & 1) ? cA1  : cA0,  src, 64);
        const int   cB  = __shfl((p & 1) ? cB1  : cB0,  src, 64);
        const float wxA = __shfl((p & 1) ? wxA1 : wxA0, src, 64);
        const float wxB = __shfl((p & 1) ? wxB1 : wxB0, src, 64);
        const float wyA = __shfl((p & 1) ? wyA1 : wyA0, src, 64);
        const float wyB = __shfl((p & 1) ? wyB1 : wyB0, src, 64);

        #pragma unroll
        for (int c = 0; c < 4; ++c) {
            const int cell  = ((c >> 1) ? rB : rA) + ((c & 1) ? cB : cA);
            const float cw  = ((c & 1) ? wxB : wxA) * ((c >> 1) ? wyB : wyA);
            const uint2 v = *(const uint2*)(hplane + ((unsigned)cell * 64u + lnoff));
            ax  = fmaf(cw, asf(v.x << 16),          ax);
            ay  = fmaf(cw, asf(v.x & 0xffff0000u),  ay);
            az  = fmaf(cw, asf(v.y << 16),          az);
            aw_ = fmaf(cw, asf(v.y & 0xffff0000u),  aw_);
        }
    }

    ushort4 o;
    o.x = f2bf(ax); o.y = f2bf(ay); o.z = f2bf(az); o.w = f2bf(aw_);
    *(ushort4*)(outh + (size_t)bq * 256 + h * 32 + lc * 4) = o;
}

// ---------------------------------------------------------------------------
// Workspace (~68.5 MB, NO aliasing; each region: one producer, later readers):
//   valueb [MQ*256 bf16]  <- gemm value (MODE1, fp32 A=enc)  -> ms_sample
//   offaw  [MQ*384 f32 ]  <- merged off+attn gemm (fp32 A=hs)-> ms_sample
//   outh   [MQ*256 bf16]  <- ms_sample                        -> gemm out
//   WvT/WcatT/WoutT       <- conv_weights                     -> gemms
// ---------------------------------------------------------------------------
extern "C" void kernel_launch(void* const* d_in, const int* in_sizes, int n_in,
                              void* d_out, int out_size, void* d_ws, size_t ws_size,
                              hipStream_t stream) {
    const float* hs   = (const float*)d_in[0];
    const float* enc  = (const float*)d_in[1];
    const float* refp = (const float*)d_in[2];
    const float* Wv   = (const float*)d_in[3];
    const float* bv   = (const float*)d_in[4];
    const float* Woff = (const float*)d_in[5];
    const float* boff = (const float*)d_in[6];
    const float* Wa   = (const float*)d_in[7];
    const float* ba   = (const float*)d_in[8];
    const float* Wout = (const float*)d_in[9];
    const float* bout = (const float*)d_in[10];

    float* out    = (float*)d_out;
    float* aw_out = out + (size_t)BQn * QN * 256;

    const size_t MQ = (size_t)BQn * QN;      // 26588
    unsigned short* valueb = (unsigned short*)d_ws;              // MQ*256 bf16
    float* offaw = (float*)(valueb + MQ * 256);                  // MQ*384 f32
    unsigned short* outh  = (unsigned short*)(offaw + MQ * 384); // MQ*256 bf16
    unsigned short* WvT   = outh + MQ * 256;                     // 256*256
    unsigned short* WcatT = WvT + 256 * 256;                     // 384*256
    unsigned short* WoutT = WcatT + 384 * 256;                   // 256*256

    const int M = (int)MQ;
    const dim3 blk(256);

    conv_weights<<<896, blk, 0, stream>>>(Wv, Woff, Wa, Wout,
                                          WvT, WcatT, WcatT + 65536, WoutT);

    const int my = (M + 127) / 128;           // 208
    gemm_mfma<256, 1, true ><<<dim3(2, my), blk, 0, stream>>>(
        enc, WvT, bv, bv, valueb, M);
    gemm_mfma<384, 0, true ><<<dim3(3, my), blk, 0, stream>>>(
        hs, WcatT, boff, ba, offaw, M);

    const int qchunks = (M + 31) / 32;        // 831
    ms_sample<<<8 * qchunks, blk, 0, stream>>>(valueb, offaw, refp,
                                               outh, aw_out);

    gemm_mfma<256, 0, false><<<dim3(2, my), blk, 0, stream>>>(
        outh, WoutT, bout, bout, out, M);
}